// Round 10
// baseline (239.063 us; speedup 1.0000x reference)
//
#include <hip/hip_runtime.h>

// CausalSelfAttention: B=8, S=2048, D=512, fp32 in/out, Q=K=V=x, no scale.
// Round 13: 32-row blocks + single-owner softmax + halved L2 traffic.
//   r12 analysis: T_tile wall ~4000cy; VALUBusy 50% @2 waves/SIMD => ~500
//   VALU inst/wave-tile (softmax duplicated x4 waves), and L2 at ~20 TB/s
//   (2.13 GB / 107us) ~= practical ceiling. Both scale with rows-per-block:
//     - 512 blocks x 256 thr; block = 32 Q-rows. K+V = 64KB per 32 rows
//       (2 KB/row, half of r12) -> L2 ~1.06 GB total.
//     - QK: wave w computes S_partial[32 rows][32 keys] over D-quarter w
//       (qf[2][4], kreg[2][4], 16 MFMA); 4-way Xc exchange (parity dbuf).
//     - softmax ONCE per row-group: wave 0 owns rows 0-15, wave 3 rows 16-31
//       (SIMD-balanced); sums full S from Xc (+own regs), masks diag,
//       defer-max(8), exp, writes shared Pw + alphaBuf + flagBuf.
//     - barrier#2; ALL waves read pa[2] from shared Pw, rescale O by flags,
//       PV over col-quarter: O[2][8] += pa[rg] x vreg[8]. 2 barriers/tile.
//     - Vf REPACKED [b][kb:64][dg:32][lane][8] so a wave's V-quarter is one
//       contiguous 8KB base (no 16-address VGPR explosion -> no spill).
//     - regs ~170 arch + 64 acc <= 256 cap @ (256,2) -> 2 blocks/CU; r0's
//       sum-65 pairing (bid<256: t=63-u heavy; else t=u light).
// ws: [0,16MiB) Kf, [16MiB,32MiB) Vf.

#define S_LEN 2048
#define D_DIM 512
#define BATCH_ELEMS 1048576  // 2 MiB bf16 per batch per array

typedef short s16x8 __attribute__((ext_vector_type(8)));
typedef float f32x4 __attribute__((ext_vector_type(4)));

__device__ __forceinline__ unsigned short f2b_rne(float f) {
  unsigned int u = __float_as_uint(f);
  return (unsigned short)((u + 0x7FFFu + ((u >> 16) & 1u)) >> 16);
}
__device__ __forceinline__ unsigned short f2b_fast(float f) {
  return (unsigned short)((__float_as_uint(f) + 0x8000u) >> 16);
}

template <int CTRL>
__device__ __forceinline__ float dppf(float x) {
  return __uint_as_float((unsigned)__builtin_amdgcn_update_dpp(
      0, (int)__float_as_uint(x), CTRL, 0xF, 0xF, true));
}
__device__ __forceinline__ float red16_max(float v) {
  v = fmaxf(v, dppf<0xB1>(v));   // xor 1
  v = fmaxf(v, dppf<0x4E>(v));   // xor 2
  v = fmaxf(v, dppf<0x124>(v));  // row_ror:4
  v = fmaxf(v, dppf<0x128>(v));  // row_ror:8
  return v;
}
__device__ __forceinline__ float red16_sum(float v) {
  v += dppf<0xB1>(v);
  v += dppf<0x4E>(v);
  v += dppf<0x124>(v);
  v += dppf<0x128>(v);
  return v;
}

// ---------------------------------------------------------------------------
// Prepass: pack x into Kf and Vf fragment order. 2048 blocks x 256 thr,
// 64x64 tile per block. A = [s][d] bf16, T = [d][s] bf16 (stride 72, 16B-al).
//   Kf[b][kg:128][db:16][lane:64][8]  elem = x[b][16*kg+l15][32*db+8*quad+j]
//   Vf[b][kb:64][dg:32][lane:64][8]   elem = x[b][32*kb+8*quad+j][16*dg+l15]
//   (Vf kb-major so a (tile, col-quarter) is 8 contiguous KB)
// ---------------------------------------------------------------------------
__global__ void pack_kernel(const float* __restrict__ x,
                            unsigned short* __restrict__ Kf,
                            unsigned short* __restrict__ Vf) {
  __shared__ unsigned short A[64 * 72];
  __shared__ unsigned short T[64 * 72];
  const int bid = blockIdx.x;
  const int b = bid >> 8, rem = bid & 255;
  const int s0 = (rem >> 3) * 64, d0 = (rem & 7) * 64;
  const int tid = threadIdx.x;

  // pass 1: load + convert, fill A[s][d]
  #pragma unroll
  for (int it = 0; it < 2; ++it) {
    int slot = it * 256 + tid;          // 0..511
    int row = slot >> 3, c = slot & 7;  // row 0..63, 8-col group
    const float* src = x + ((size_t)(b * S_LEN + s0 + row)) * D_DIM + d0 + c * 8;
    const float4 v0 = *(const float4*)(src);
    const float4 v1 = *(const float4*)(src + 4);
    s16x8 o;
    o[0] = (short)f2b_rne(v0.x); o[1] = (short)f2b_rne(v0.y);
    o[2] = (short)f2b_rne(v0.z); o[3] = (short)f2b_rne(v0.w);
    o[4] = (short)f2b_rne(v1.x); o[5] = (short)f2b_rne(v1.y);
    o[6] = (short)f2b_rne(v1.z); o[7] = (short)f2b_rne(v1.w);
    *(s16x8*)&A[row * 72 + c * 8] = o;
  }
  __syncthreads();

  // pass 2: transpose A -> T in 4x4 micro-blocks (vector b64 ops)
  {
    int sr = tid >> 4, sc = tid & 15;
    ushort4 a0 = *(const ushort4*)&A[(4 * sr + 0) * 72 + 4 * sc];
    ushort4 a1 = *(const ushort4*)&A[(4 * sr + 1) * 72 + 4 * sc];
    ushort4 a2 = *(const ushort4*)&A[(4 * sr + 2) * 72 + 4 * sc];
    ushort4 a3 = *(const ushort4*)&A[(4 * sr + 3) * 72 + 4 * sc];
    ushort4 t0; t0.x = a0.x; t0.y = a1.x; t0.z = a2.x; t0.w = a3.x;
    ushort4 t1; t1.x = a0.y; t1.y = a1.y; t1.z = a2.y; t1.w = a3.y;
    ushort4 t2; t2.x = a0.z; t2.y = a1.z; t2.z = a2.z; t2.w = a3.z;
    ushort4 t3; t3.x = a0.w; t3.y = a1.w; t3.z = a2.w; t3.w = a3.w;
    *(ushort4*)&T[(4 * sc + 0) * 72 + 4 * sr] = t0;
    *(ushort4*)&T[(4 * sc + 1) * 72 + 4 * sr] = t1;
    *(ushort4*)&T[(4 * sc + 2) * 72 + 4 * sr] = t2;
    *(ushort4*)&T[(4 * sc + 3) * 72 + 4 * sr] = t3;
  }
  __syncthreads();

  // pass 3: emit fragment blocks (each 64 consecutive threads write 1KB)
  #pragma unroll
  for (int it = 0; it < 2; ++it) {
    int slot = it * 256 + tid;
    int frag = slot >> 6;               // 0..7
    int lane = slot & 63;
    int l15 = lane & 15, quad = lane >> 4;
    int f1 = frag >> 1, f0 = frag & 1;  // f1: 0..3, f0: 0..1
    // Kf: kgl=f1 (16 rows), dbl=f0 (32 cols)
    {
      s16x8 val = *(const s16x8*)&A[(f1 * 16 + l15) * 72 + f0 * 32 + quad * 8];
      size_t kg = (size_t)(s0 >> 4) + f1, db = (size_t)(d0 >> 5) + f0;
      *(s16x8*)(Kf + (size_t)b * BATCH_ELEMS + (kg * 16 + db) * 512 + lane * 8) = val;
    }
    // Vf (kb-major): dgl=f1 (16 cols), kbl=f0 (32 rows)
    {
      s16x8 val = *(const s16x8*)&T[(f1 * 16 + l15) * 72 + f0 * 32 + quad * 8];
      size_t dg = (size_t)(d0 >> 4) + f1, kb = (size_t)(s0 >> 5) + f0;
      *(s16x8*)(Vf + (size_t)b * BATCH_ELEMS + (kb * 32 + dg) * 512 + lane * 8) = val;
    }
  }
}

// ---------------------------------------------------------------------------
// Flash attention: 32-row blocks, 4 waves; QK by D-quarter (K in regs,
// exchange-summed), softmax single-owner per 16-row group (waves 0 & 3),
// PV by col-quarter (V in regs, shared pa from LDS).
// MFMA 16x16x32 layouts: A[m=l15][k=quad*8+j], B[k=quad*8+j][n=l15],
// C/D: col=l15, row=quad*4+reg.
// ---------------------------------------------------------------------------
__global__ __launch_bounds__(256, 2)
void attn_kernel(const unsigned short* __restrict__ Kf,
                 const unsigned short* __restrict__ Vf,
                 float* __restrict__ out) {
  __shared__ float Xc[2][4][1024];        // [parity][wave][(rg*2+kg)*256+lane*4]
  __shared__ unsigned short Pw[2][32 * 40];
  __shared__ float alphaBuf[2][32];
  __shared__ int flagBuf[2][2];
  __shared__ float lBuf[32];

  const int bid = blockIdx.x;
  const int bat = bid & 7;                // batch == XCD under round-robin
  const int t = (bid < 256) ? (63 - (bid >> 3)) : ((bid - 256) >> 3);
  const int q0 = t * 32;
  const int tmax = t;                     // tiles 0..t
  const int tid = threadIdx.x;
  const int w = tid >> 6;                 // 0..3: D-quarter (QK) / col-quarter (PV)
  const int lane = tid & 63;
  const int l15 = lane & 15, quad = lane >> 4;
  const size_t batOff = (size_t)bat * BATCH_ELEMS;
  const int srg = (w == 0) ? 0 : ((w == 3) ? 1 : -1);  // owned softmax row-group

  // K frags for D-quarter w, both key-groups: (kg=2kt+g, db=w*4+i)
  s16x8 kreg[2][4];
  auto loadK = [&](int kt) {
    const unsigned short* kb =
        Kf + batOff + (size_t)kt * 16384 + (size_t)(w * 4) * 512 + lane * 8;
    #pragma unroll
    for (int g = 0; g < 2; ++g)
      #pragma unroll
      for (int i = 0; i < 4; ++i)
        kreg[g][i] = *(const s16x8*)(kb + (size_t)(g * 16 + i) * 512);
  };

  // V frags for col-quarter w (contiguous 8KB under kb-major layout)
  s16x8 vreg[8];
  auto loadV = [&](int kt) {
    const unsigned short* vb =
        Vf + batOff + ((size_t)kt * 32 + w * 8) * 512 + lane * 8;
    #pragma unroll
    for (int d = 0; d < 8; ++d)
      vreg[d] = *(const s16x8*)(vb + (size_t)d * 512);
  };

  loadK(0);
  loadV(0);

  // Q frags: rows q0..q0+31 (rg halves), D-quarter w
  s16x8 qf[2][4];
  {
    const unsigned short* qb =
        Kf + batOff + ((size_t)(2 * t) * 16 + w * 4) * 512 + lane * 8;
    #pragma unroll
    for (int rg = 0; rg < 2; ++rg)
      #pragma unroll
      for (int i = 0; i < 4; ++i)
        qf[rg][i] = *(const s16x8*)(qb + (size_t)(rg * 16 + i) * 512);
  }

  f32x4 O[2][8];
  #pragma unroll
  for (int rg = 0; rg < 2; ++rg)
    #pragma unroll
    for (int d = 0; d < 8; ++d) O[rg][d] = (f32x4){0.f, 0.f, 0.f, 0.f};
  float m[4], l[4];
  #pragma unroll
  for (int r = 0; r < 4; ++r) { m[r] = -3e38f; l[r] = 0.f; }

  for (int kt = 0;; ++kt) {
    const int p = kt & 1;

    // ---- QK^T partial: S_q[32 rows][32 keys] over D-quarter w ----
    f32x4 sacc[2][2];
    #pragma unroll
    for (int rg = 0; rg < 2; ++rg)
      #pragma unroll
      for (int g = 0; g < 2; ++g) sacc[rg][g] = (f32x4){0.f, 0.f, 0.f, 0.f};
    __builtin_amdgcn_s_setprio(1);
    #pragma unroll
    for (int i = 0; i < 4; ++i) {
      sacc[0][0] = __builtin_amdgcn_mfma_f32_16x16x32_bf16(qf[0][i], kreg[0][i], sacc[0][0], 0, 0, 0);
      sacc[0][1] = __builtin_amdgcn_mfma_f32_16x16x32_bf16(qf[0][i], kreg[1][i], sacc[0][1], 0, 0, 0);
      sacc[1][0] = __builtin_amdgcn_mfma_f32_16x16x32_bf16(qf[1][i], kreg[0][i], sacc[1][0], 0, 0, 0);
      sacc[1][1] = __builtin_amdgcn_mfma_f32_16x16x32_bf16(qf[1][i], kreg[1][i], sacc[1][1], 0, 0, 0);
    }
    __builtin_amdgcn_s_setprio(0);

    if (kt < tmax) loadK(kt + 1);  // prefetch K(t+1), WAR pins after QK

    // ---- publish partials; barrier#1 ----
    #pragma unroll
    for (int rg = 0; rg < 2; ++rg)
      #pragma unroll
      for (int g = 0; g < 2; ++g)
        *(f32x4*)&Xc[p][w][(rg * 2 + g) * 256 + lane * 4] = sacc[rg][g];
    asm volatile("s_waitcnt lgkmcnt(0)" ::: "memory");
    __builtin_amdgcn_s_barrier();
    __builtin_amdgcn_sched_barrier(0);

    // ---- single-owner softmax (waves 0 and 3) ----
    if (srg >= 0) {
      f32x4 s0 = sacc[srg][0], s1 = sacc[srg][1];
      #pragma unroll
      for (int ww = 0; ww < 4; ++ww) {
        if (ww != w) {
          s0 += *(const f32x4*)&Xc[p][ww][(srg * 2 + 0) * 256 + lane * 4];
          s1 += *(const f32x4*)&Xc[p][ww][(srg * 2 + 1) * 256 + lane * 4];
        }
      }
      if (kt == tmax) {  // causal mask: key g*16+l15 > row srg*16+quad*4+r
        #pragma unroll
        for (int r = 0; r < 4; ++r) {
          int row = srg * 16 + quad * 4 + r;
          if (l15 > row) s0[r] = -3e38f;
          if (16 + l15 > row) s1[r] = -3e38f;
        }
      }
      float mt[4], alpha[4];
      #pragma unroll
      for (int r = 0; r < 4; ++r) mt[r] = red16_max(fmaxf(s0[r], s1[r]));
      bool needAny = (mt[0] > m[0] + 8.f) | (mt[1] > m[1] + 8.f) |
                     (mt[2] > m[2] + 8.f) | (mt[3] > m[3] + 8.f);
      unsigned long long bal = __ballot(needAny);
      if (bal) {
        #pragma unroll
        for (int r = 0; r < 4; ++r) {
          float mn = fmaxf(m[r], mt[r]);
          alpha[r] = __expf(m[r] - mn);
          m[r] = mn;
        }
      }
      float e0[4], e1[4];
      #pragma unroll
      for (int r = 0; r < 4; ++r) {
        e0[r] = __expf(s0[r] - m[r]);
        e1[r] = __expf(s1[r] - m[r]);
      }
      #pragma unroll
      for (int r = 0; r < 4; ++r) {
        float lp = bal ? l[r] * alpha[r] : l[r];
        l[r] = lp + red16_sum(e0[r] + e1[r]);
      }
      // shared P (A-layout source), alpha, flag
      #pragma unroll
      for (int r = 0; r < 4; ++r) {
        int row = srg * 16 + quad * 4 + r;
        Pw[p][row * 40 + l15] = f2b_fast(e0[r]);
        Pw[p][row * 40 + 16 + l15] = f2b_fast(e1[r]);
      }
      if (bal) {
        #pragma unroll
        for (int r = 0; r < 4; ++r)
          alphaBuf[p][srg * 16 + quad * 4 + r] = alpha[r];  // dup-write, same value
      }
      if (lane == 0) flagBuf[p][srg] = bal ? 1 : 0;
    }
    asm volatile("s_waitcnt lgkmcnt(0)" ::: "memory");
    __builtin_amdgcn_s_barrier();
    __builtin_amdgcn_sched_barrier(0);

    // ---- rescale O by flags (rare after defer-max) ----
    {
      int f0 = flagBuf[p][0];
      int f1 = flagBuf[p][1];
      if (f0) {
        f32x4 a = *(const f32x4*)&alphaBuf[p][quad * 4];
        #pragma unroll
        for (int d = 0; d < 8; ++d)
          #pragma unroll
          for (int r = 0; r < 4; ++r) O[0][d][r] *= a[r];
      }
      if (f1) {
        f32x4 a = *(const f32x4*)&alphaBuf[p][16 + quad * 4];
        #pragma unroll
        for (int d = 0; d < 8; ++d)
          #pragma unroll
          for (int r = 0; r < 4; ++r) O[1][d][r] *= a[r];
      }
    }

    // ---- PV: O[rg][16 rows][col-quarter w] += P(16x32) x V-quarter ----
    s16x8 pa0 = *(const s16x8*)&Pw[p][l15 * 40 + quad * 8];
    s16x8 pa1 = *(const s16x8*)&Pw[p][(16 + l15) * 40 + quad * 8];
    __builtin_amdgcn_s_setprio(1);
    #pragma unroll
    for (int d = 0; d < 8; ++d)
      O[0][d] = __builtin_amdgcn_mfma_f32_16x16x32_bf16(pa0, vreg[d], O[0][d], 0, 0, 0);
    #pragma unroll
    for (int d = 0; d < 8; ++d)
      O[1][d] = __builtin_amdgcn_mfma_f32_16x16x32_bf16(pa1, vreg[d], O[1][d], 0, 0, 0);
    __builtin_amdgcn_s_setprio(0);

    if (kt == tmax) break;
    loadV(kt + 1);  // prefetch V(t+1), WAR pins after PV
  }

  // ---- epilogue: owners publish 1/l; everyone normalizes & stores ----
  if (srg >= 0) {
    #pragma unroll
    for (int r = 0; r < 4; ++r)
      lBuf[srg * 16 + quad * 4 + r] = 1.0f / l[r];  // dup-write, same value
  }
  asm volatile("s_waitcnt lgkmcnt(0)" ::: "memory");
  __builtin_amdgcn_s_barrier();
  __builtin_amdgcn_sched_barrier(0);
  f32x4 il0 = *(const f32x4*)&lBuf[quad * 4];
  f32x4 il1 = *(const f32x4*)&lBuf[16 + quad * 4];
  float* ob = out + ((size_t)(bat * S_LEN + q0)) * D_DIM + w * 128;
  #pragma unroll
  for (int d = 0; d < 8; ++d)
    #pragma unroll
    for (int r = 0; r < 4; ++r) {
      ob[(size_t)(quad * 4 + r) * D_DIM + d * 16 + l15] = O[0][d][r] * il0[r];
      ob[(size_t)(16 + quad * 4 + r) * D_DIM + d * 16 + l15] = O[1][d][r] * il1[r];
    }
}

extern "C" void kernel_launch(void* const* d_in, const int* in_sizes, int n_in,
                              void* d_out, int out_size, void* d_ws, size_t ws_size,
                              hipStream_t stream) {
  (void)in_sizes; (void)n_in; (void)out_size; (void)ws_size;
  const float* x = (const float*)d_in[0];
  float* out = (float*)d_out;
  unsigned short* Kf = (unsigned short*)d_ws;                         // 16 MiB
  unsigned short* Vf = (unsigned short*)((char*)d_ws + (16u << 20));  // 16 MiB
  pack_kernel<<<2048, 256, 0, stream>>>(x, Kf, Vf);
  attn_kernel<<<512, 256, 0, stream>>>(Kf, Vf, out);
}

// Round 12
// 161.430 us; speedup vs baseline: 1.4809x; 1.4809x over previous
//
#include <hip/hip_runtime.h>

// CausalSelfAttention: B=8, S=2048, D=512, fp32 in/out, Q=K=V=x, no scale.
// Round 15: identical to r14 (bench was an infra failure — container
// acquisition failed twice; no kernel verdict). Re-running unchanged.
//   r14 design: r10 skeleton (best: 103us) + 64-key tiles + l-via-MFMA.
//   r13 post-mortem: single-owner softmax = 2 barriers + idle waves -> 167us.
//   Locked lesson: duplicated wave-local softmax + ONE barrier wins. r12
//   showed occupancy is not the lever; per-tile FIXED latencies are
//   (exchange round-trip ~300cy, Pw ~150cy, barrier skew, exp chains).
//   Changes vs r10 (structure unchanged: 1024 blocks x 256 thr, 16-row
//   block, QK by D-quarter + 4-way Xc exchange, PV by col-quarter, K/V in
//   regs prefetched behind WAR deps, ONE barrier/iter, Xc parity dbuf):
//     - 64-key tiles (kg 0..3 per iter): halves per-key share of all fixed
//       costs. kreg[16], vreg[2][8], sacc[4], Pw 16x64 (stride 72).
//     - l via ones-MFMA: linc = mfma(pa23,ones, mfma(pa01,ones,0)) puts each
//       row's sum in that row's lanes (C/D row=quad*4+r) -> replaces
//       red16_sum x4 (32 inst) with 2 MFMA. l matches bf16 P used in PV.
//     - Kf quarter-major [b][dq:4][kg:128][dbl:4][lane][8]: wave's K tile =
//       one contiguous 16KB base. Vf kb-major (r13): V = 2 bases.
//     - defer-max(8) kept; duplicated softmax kept; no loop-end barrier.
//   Regs ~220 unified < 256 @ (256,2). WRITE_SIZE==32768 is the spill canary.
// ws: [0,16MiB) Kf, [16MiB,32MiB) Vf.

#define S_LEN 2048
#define D_DIM 512
#define BATCH_ELEMS 1048576  // 2 MiB bf16 per batch per array

typedef short s16x8 __attribute__((ext_vector_type(8)));
typedef float f32x4 __attribute__((ext_vector_type(4)));

__device__ __forceinline__ unsigned short f2b_rne(float f) {
  unsigned int u = __float_as_uint(f);
  return (unsigned short)((u + 0x7FFFu + ((u >> 16) & 1u)) >> 16);
}
__device__ __forceinline__ unsigned short f2b_fast(float f) {
  return (unsigned short)((__float_as_uint(f) + 0x8000u) >> 16);
}

template <int CTRL>
__device__ __forceinline__ float dppf(float x) {
  return __uint_as_float((unsigned)__builtin_amdgcn_update_dpp(
      0, (int)__float_as_uint(x), CTRL, 0xF, 0xF, true));
}
__device__ __forceinline__ float red16_max(float v) {
  v = fmaxf(v, dppf<0xB1>(v));   // xor 1
  v = fmaxf(v, dppf<0x4E>(v));   // xor 2
  v = fmaxf(v, dppf<0x124>(v));  // row_ror:4
  v = fmaxf(v, dppf<0x128>(v));  // row_ror:8
  return v;
}

// ---------------------------------------------------------------------------
// Prepass: pack x into Kf (quarter-major) and Vf (kb-major) fragment order.
// 2048 blocks x 256 thr, 64x64 tile per block.
//   Kf[b][dq:4][kg:128][dbl:4][lane:64][8]
//       elem = x[b][16*kg+l15][32*(4dq+dbl)+8*quad+j]
//   Vf[b][kb:64][dg:32][lane:64][8]   elem = x[b][32*kb+8*quad+j][16*dg+l15]
// ---------------------------------------------------------------------------
__global__ void pack_kernel(const float* __restrict__ x,
                            unsigned short* __restrict__ Kf,
                            unsigned short* __restrict__ Vf) {
  __shared__ unsigned short A[64 * 72];
  __shared__ unsigned short T[64 * 72];
  const int bid = blockIdx.x;
  const int b = bid >> 8, rem = bid & 255;
  const int s0 = (rem >> 3) * 64, d0 = (rem & 7) * 64;
  const int tid = threadIdx.x;

  // pass 1: load + convert, fill A[s][d]
  #pragma unroll
  for (int it = 0; it < 2; ++it) {
    int slot = it * 256 + tid;          // 0..511
    int row = slot >> 3, c = slot & 7;  // row 0..63, 8-col group
    const float* src = x + ((size_t)(b * S_LEN + s0 + row)) * D_DIM + d0 + c * 8;
    const float4 v0 = *(const float4*)(src);
    const float4 v1 = *(const float4*)(src + 4);
    s16x8 o;
    o[0] = (short)f2b_rne(v0.x); o[1] = (short)f2b_rne(v0.y);
    o[2] = (short)f2b_rne(v0.z); o[3] = (short)f2b_rne(v0.w);
    o[4] = (short)f2b_rne(v1.x); o[5] = (short)f2b_rne(v1.y);
    o[6] = (short)f2b_rne(v1.z); o[7] = (short)f2b_rne(v1.w);
    *(s16x8*)&A[row * 72 + c * 8] = o;
  }
  __syncthreads();

  // pass 2: transpose A -> T in 4x4 micro-blocks (vector b64 ops)
  {
    int sr = tid >> 4, sc = tid & 15;
    ushort4 a0 = *(const ushort4*)&A[(4 * sr + 0) * 72 + 4 * sc];
    ushort4 a1 = *(const ushort4*)&A[(4 * sr + 1) * 72 + 4 * sc];
    ushort4 a2 = *(const ushort4*)&A[(4 * sr + 2) * 72 + 4 * sc];
    ushort4 a3 = *(const ushort4*)&A[(4 * sr + 3) * 72 + 4 * sc];
    ushort4 t0; t0.x = a0.x; t0.y = a1.x; t0.z = a2.x; t0.w = a3.x;
    ushort4 t1; t1.x = a0.y; t1.y = a1.y; t1.z = a2.y; t1.w = a3.y;
    ushort4 t2; t2.x = a0.z; t2.y = a1.z; t2.z = a2.z; t2.w = a3.z;
    ushort4 t3; t3.x = a0.w; t3.y = a1.w; t3.z = a2.w; t3.w = a3.w;
    *(ushort4*)&T[(4 * sc + 0) * 72 + 4 * sr] = t0;
    *(ushort4*)&T[(4 * sc + 1) * 72 + 4 * sr] = t1;
    *(ushort4*)&T[(4 * sc + 2) * 72 + 4 * sr] = t2;
    *(ushort4*)&T[(4 * sc + 3) * 72 + 4 * sr] = t3;
  }
  __syncthreads();

  // pass 3: emit fragment blocks (each 64 consecutive threads write 1KB)
  #pragma unroll
  for (int it = 0; it < 2; ++it) {
    int slot = it * 256 + tid;
    int frag = slot >> 6;               // 0..7
    int lane = slot & 63;
    int l15 = lane & 15, quad = lane >> 4;
    int f1 = frag >> 1, f0 = frag & 1;  // f1: 0..3, f0: 0..1
    // Kf (quarter-major): kg=(s0>>4)+f1, db=(d0>>5)+f0 -> dq=db>>2, dbl=db&3
    {
      s16x8 val = *(const s16x8*)&A[(f1 * 16 + l15) * 72 + f0 * 32 + quad * 8];
      size_t kg = (size_t)(s0 >> 4) + f1;
      int db = (d0 >> 5) + f0;
      size_t dq = (size_t)(db >> 2), dbl = (size_t)(db & 3);
      *(s16x8*)(Kf + (size_t)b * BATCH_ELEMS +
                ((dq * 128 + kg) * 4 + dbl) * 512 + lane * 8) = val;
    }
    // Vf (kb-major): dgl=f1 (16 cols), kbl=f0 (32 rows)
    {
      s16x8 val = *(const s16x8*)&T[(f1 * 16 + l15) * 72 + f0 * 32 + quad * 8];
      size_t dg = (size_t)(d0 >> 4) + f1, kb = (size_t)(s0 >> 5) + f0;
      *(s16x8*)(Vf + (size_t)b * BATCH_ELEMS + (kb * 32 + dg) * 512 + lane * 8) = val;
    }
  }
}

// ---------------------------------------------------------------------------
// Flash attention: 16-row blocks, 4 waves quarter-D QK (K in regs, 4-way
// exchange-summed) / quarter-col PV (V in regs), 64-key tiles, l via MFMA.
// MFMA 16x16x32 layouts: A[m=l15][k=quad*8+j], B[k=quad*8+j][n=l15],
// C/D: col=l15, row=quad*4+reg.
// ---------------------------------------------------------------------------
__global__ __launch_bounds__(256, 2)
void attn_kernel(const unsigned short* __restrict__ Kf,
                 const unsigned short* __restrict__ Vf,
                 float* __restrict__ out) {
  __shared__ float Xc[2][4][1024];          // [parity][wave][kg*256+lane*4]
  __shared__ unsigned short Pw[4][16 * 72]; // wave-private P (16x64, pad 72)

  const int bid = blockIdx.x;
  const int bat = bid & 7;                // batch == XCD under round-robin
  const int rg = 127 - (bid >> 3);        // smooth + LPT (heaviest first)
  const int q0 = rg * 16;
  const int tmax = rg >> 2;               // 64-key tiles: 0..tmax
  const int tid = threadIdx.x;
  const int w = tid >> 6;                 // 0..3: D-quarter / col-quarter
  const int lane = tid & 63;
  const int l15 = lane & 15, quad = lane >> 4;
  const size_t batOff = (size_t)bat * BATCH_ELEMS;

  s16x8 ones;
  #pragma unroll
  for (int j = 0; j < 8; ++j) ones[j] = (short)0x3F80;  // bf16 1.0

  // K frags: D-quarter w, kg = 4kt+g, dbl = i. One contiguous 16KB base.
  s16x8 kreg[16];
  auto loadK = [&](int kt) {
    const unsigned short* kb =
        Kf + batOff + ((size_t)(w * 128 + 4 * kt) * 4) * 512 + lane * 8;
    #pragma unroll
    for (int f = 0; f < 16; ++f)
      kreg[f] = *(const s16x8*)(kb + (size_t)f * 512);
  };

  // V frags: col-quarter w (dg = w*8+d), kb = 2kt (+1). Two contiguous bases.
  s16x8 vreg[2][8];
  auto loadV = [&](int kt) {
    const unsigned short* vb =
        Vf + batOff + ((size_t)(2 * kt) * 32 + w * 8) * 512 + lane * 8;
    #pragma unroll
    for (int d = 0; d < 8; ++d) {
      vreg[0][d] = *(const s16x8*)(vb + (size_t)d * 512);
      vreg[1][d] = *(const s16x8*)(vb + (size_t)(32 + d) * 512);
    }
  };

  loadK(0);
  loadV(0);

  // Q frags: rows q0..q0+15 (kg index = rg), D-quarter w.
  s16x8 qf[4];
  {
    const unsigned short* qb =
        Kf + batOff + ((size_t)(w * 128 + rg) * 4) * 512 + lane * 8;
    #pragma unroll
    for (int i = 0; i < 4; ++i) qf[i] = *(const s16x8*)(qb + (size_t)i * 512);
  }

  f32x4 O[8];
  float m[4], l[4];
  #pragma unroll
  for (int n = 0; n < 8; ++n) O[n] = (f32x4){0.f, 0.f, 0.f, 0.f};
  #pragma unroll
  for (int r = 0; r < 4; ++r) { m[r] = -3e38f; l[r] = 0.f; }

  for (int kt = 0;; ++kt) {
    const int p = kt & 1;

    // ---- QK^T partial: S_q[16 rows][64 keys] over D-quarter w ----
    f32x4 sacc[4];
    #pragma unroll
    for (int g = 0; g < 4; ++g) sacc[g] = (f32x4){0.f, 0.f, 0.f, 0.f};
    __builtin_amdgcn_s_setprio(1);
    #pragma unroll
    for (int g = 0; g < 4; ++g)
      #pragma unroll
      for (int i = 0; i < 4; ++i)
        sacc[g] = __builtin_amdgcn_mfma_f32_16x16x32_bf16(qf[i], kreg[g * 4 + i],
                                                          sacc[g], 0, 0, 0);
    __builtin_amdgcn_s_setprio(0);

    if (kt < tmax) loadK(kt + 1);  // prefetch K(t+1), WAR pins after QK

    // ---- 4-way exchange: publish, ONE barrier, fixed-order sum ----
    #pragma unroll
    for (int g = 0; g < 4; ++g)
      *(f32x4*)&Xc[p][w][g * 256 + lane * 4] = sacc[g];
    asm volatile("s_waitcnt lgkmcnt(0)" ::: "memory");
    __builtin_amdgcn_s_barrier();
    __builtin_amdgcn_sched_barrier(0);
    {
      f32x4 a0[4];
      #pragma unroll
      for (int g = 0; g < 4; ++g) a0[g] = sacc[g];
      #pragma unroll
      for (int ww = 0; ww < 4; ++ww) {
        if (ww == w) continue;
        #pragma unroll
        for (int g = 0; g < 4; ++g)
          a0[g] += *(const f32x4*)&Xc[p][ww][g * 256 + lane * 4];
      }
      #pragma unroll
      for (int g = 0; g < 4; ++g) sacc[g] = a0[g];
    }

    if (kt == tmax) {  // causal mask on diagonal tile
      #pragma unroll
      for (int g = 0; g < 4; ++g)
        #pragma unroll
        for (int r = 0; r < 4; ++r) {
          int key = kt * 64 + g * 16 + l15;
          int row = q0 + quad * 4 + r;
          if (key > row) sacc[g][r] = -3e38f;
        }
    }

    // ---- online softmax (registers + DPP; identical in all 4 waves) ----
    float mt[4], alpha[4];
    #pragma unroll
    for (int r = 0; r < 4; ++r)
      mt[r] = red16_max(fmaxf(fmaxf(sacc[0][r], sacc[1][r]),
                              fmaxf(sacc[2][r], sacc[3][r])));
    bool needAny = (mt[0] > m[0] + 8.f) | (mt[1] > m[1] + 8.f) |
                   (mt[2] > m[2] + 8.f) | (mt[3] > m[3] + 8.f);
    unsigned long long bal = __ballot(needAny);
    if (bal) {
      #pragma unroll
      for (int r = 0; r < 4; ++r) {
        float mn = fmaxf(m[r], mt[r]);
        alpha[r] = __expf(m[r] - mn);
        m[r] = mn;
      }
    }

    // ---- P = exp(S-m) -> bf16 -> wave-private Pw (A-layout source) ----
    #pragma unroll
    for (int g = 0; g < 4; ++g)
      #pragma unroll
      for (int r = 0; r < 4; ++r) {
        float e = __expf(sacc[g][r] - m[r]);
        Pw[w][(quad * 4 + r) * 72 + g * 16 + l15] = f2b_fast(e);
      }
    s16x8 pa01 = *(const s16x8*)&Pw[w][l15 * 72 + quad * 8];
    s16x8 pa23 = *(const s16x8*)&Pw[w][l15 * 72 + 32 + quad * 8];

    if (bal) {
      #pragma unroll
      for (int n = 0; n < 8; ++n)
        #pragma unroll
        for (int r = 0; r < 4; ++r) O[n][r] *= alpha[r];
    }

    // ---- PV + l-increment via ones-MFMA ----
    __builtin_amdgcn_s_setprio(1);
    #pragma unroll
    for (int d = 0; d < 8; ++d) {
      O[d] = __builtin_amdgcn_mfma_f32_16x16x32_bf16(pa01, vreg[0][d], O[d], 0, 0, 0);
      O[d] = __builtin_amdgcn_mfma_f32_16x16x32_bf16(pa23, vreg[1][d], O[d], 0, 0, 0);
    }
    f32x4 linc = (f32x4){0.f, 0.f, 0.f, 0.f};
    linc = __builtin_amdgcn_mfma_f32_16x16x32_bf16(pa01, ones, linc, 0, 0, 0);
    linc = __builtin_amdgcn_mfma_f32_16x16x32_bf16(pa23, ones, linc, 0, 0, 0);
    __builtin_amdgcn_s_setprio(0);
    #pragma unroll
    for (int r = 0; r < 4; ++r)
      l[r] = (bal ? l[r] * alpha[r] : l[r]) + linc[r];

    if (kt == tmax) break;
    loadV(kt + 1);  // prefetch V(t+1), WAR pins after PV
  }

  // ---- epilogue: wave writes its 16 rows x 128-col quarter ----
  float invl[4];
  #pragma unroll
  for (int r = 0; r < 4; ++r) invl[r] = 1.0f / l[r];
  float* ob = out + ((size_t)(bat * S_LEN + q0)) * D_DIM + w * 128;
  #pragma unroll
  for (int d = 0; d < 8; ++d)
    #pragma unroll
    for (int r = 0; r < 4; ++r)
      ob[(size_t)(quad * 4 + r) * D_DIM + d * 16 + l15] = O[d][r] * invl[r];
}

extern "C" void kernel_launch(void* const* d_in, const int* in_sizes, int n_in,
                              void* d_out, int out_size, void* d_ws, size_t ws_size,
                              hipStream_t stream) {
  (void)in_sizes; (void)n_in; (void)out_size; (void)ws_size;
  const float* x = (const float*)d_in[0];
  float* out = (float*)d_out;
  unsigned short* Kf = (unsigned short*)d_ws;                         // 16 MiB
  unsigned short* Vf = (unsigned short*)((char*)d_ws + (16u << 20));  // 16 MiB
  pack_kernel<<<2048, 256, 0, stream>>>(x, Kf, Vf);
  attn_kernel<<<1024, 256, 0, stream>>>(Kf, Vf, out);
}